// Round 11
// baseline (172.797 us; speedup 1.0000x reference)
//
#include <hip/hip_runtime.h>

// Gated delta rule recurrence S_t = S_{t-1} @ A_t + B_t, outputs all S_t.
// T=128, B*H=64 chains, D=64. Two-level chunked scan, NC=16 chunks of CH=8.
//   K1 (fold): chunk summaries (PA,PB)           [1024 blocks x 7 steps]
//   K2 (scan): over 16 summaries -> chunk-end states into out [64 blocks]
//   K3 (scan): in-chunk recurrence -> remaining states        [1024 blocks]
// Split-bf16 MFMA (hi/lo, 3 products), transposed recurrence S^T <- A^T S^T.
// r11: DEPTH-2 PIPELINE with counted vmcnt (never 0 in the loop):
//   - A: triple-buffered LDS (sA[3], 48KB), DMA'd linear+coalesced via
//     global_load_lds; A(i+2) issued at step i, consumed at step i+2.
//   - B: two named register sets (2-unrolled loop, static names).
//   - per-step issue order [B, A] + sched_barrier fences, so consuming B(i)
//     never drains the newer A DMAs (vmcnt FIFO semantics).
//   - step-end: s_waitcnt vmcnt(8) (fold) / vmcnt(12) (scan: +4 stores) +
//     raw s_barrier -> exactly the next step's A-tile drained, newest
//     batches stay in flight ACROSS the barrier.
// Tail issues clamped (uniform counts). waves_per_eu(3,4): LDS-capped at
// 3 blocks/CU, big VGPR budget (no spill-for-occupancy).

constexpr int kT = 128;
constexpr int kBH = 64;
constexpr int kD = 64;
constexpr int kTile = kD * kD;
constexpr int kNC = 16;
constexpr int kCH = 8;

typedef __attribute__((ext_vector_type(8))) short short8;
typedef __attribute__((ext_vector_type(4))) float f32x4;
using u32 = unsigned int;

union U8 { u32 u[4]; short8 s; };

__device__ __forceinline__ f32x4 mfma16(short8 a, short8 b, f32x4 c) {
  return __builtin_amdgcn_mfma_f32_16x16x32_bf16(a, b, c, 0, 0, 0);
}

// split 2 floats into packed hi/lo bf16 pairs (1 v_cvt_pk each + exact residual)
__device__ __forceinline__ void pk_split(float a, float b, u32& h, u32& l) {
  u32 hu;
  asm("v_cvt_pk_bf16_f32 %0, %1, %2" : "=v"(hu) : "v"(a), "v"(b));
  const float ra = a - __uint_as_float(hu << 16);
  const float rb = b - __uint_as_float(hu & 0xffff0000u);
  u32 lu;
  asm("v_cvt_pk_bf16_f32 %0, %1, %2" : "=v"(lu) : "v"(ra), "v"(rb));
  h = hu;
  l = lu;
}

// Build one K=32 B-operand fragment from two C/D tiles (X = tile 2ks, Y = 2ks+1).
__device__ __forceinline__ short8 gather_frag(u32 p01, u32 p23, u32 q01, u32 q23,
                                              int ad0, int ad1, bool lowh) {
  U8 r;
  int x, y;
  x = __builtin_amdgcn_ds_bpermute(ad0, (int)p01);
  y = __builtin_amdgcn_ds_bpermute(ad0, (int)q01);
  r.u[0] = (u32)(lowh ? x : y);
  x = __builtin_amdgcn_ds_bpermute(ad0, (int)p23);
  y = __builtin_amdgcn_ds_bpermute(ad0, (int)q23);
  r.u[1] = (u32)(lowh ? x : y);
  x = __builtin_amdgcn_ds_bpermute(ad1, (int)p01);
  y = __builtin_amdgcn_ds_bpermute(ad1, (int)q01);
  r.u[2] = (u32)(lowh ? x : y);
  x = __builtin_amdgcn_ds_bpermute(ad1, (int)p23);
  y = __builtin_amdgcn_ds_bpermute(ad1, (int)q23);
  r.u[3] = (u32)(lowh ? x : y);
  return r.s;
}

// Read A^T fragment (rows = A cols) from LINEAR row-major fp32 A tile in LDS:
// need A[k0+j][row], j=0..7 -> LDS dword (k0+j)*64 + row.
__device__ __forceinline__ void read_afragT(const float* sAbuf, int row, int k0,
                                            short8& ah, short8& al) {
  const float* base = sAbuf + k0 * 64 + row;
  float d0 = base[0], d1 = base[64], d2 = base[128], d3 = base[192];
  float d4 = base[256], d5 = base[320], d6 = base[384], d7 = base[448];
  U8 h, l;
  u32 hu, lu;
  pk_split(d0, d1, hu, lu); h.u[0] = hu; l.u[0] = lu;
  pk_split(d2, d3, hu, lu); h.u[1] = hu; l.u[1] = lu;
  pk_split(d4, d5, hu, lu); h.u[2] = hu; l.u[2] = lu;
  pk_split(d6, d7, hu, lu); h.u[3] = hu; l.u[3] = lu;
  ah = h.s; al = l.s;
}

// Issue 4 coalesced global_load_lds (width 16): this wave's 4KB quarter of the
// A tile, linear row-major (src 1KB contiguous per inst, zero registers).
#define ISSUE_A(PTRA, SBUF)                                                     \
  do {                                                                          \
    const float* gp_ = (PTRA);                                                  \
    float* sb_ = (SBUF);                                                        \
    _Pragma("unroll") for (int it_ = 0; it_ < 4; ++it_) {                       \
      const int off_ = (w * 4 + it_) * 256;                                     \
      __builtin_amdgcn_global_load_lds(                                         \
          (const __attribute__((address_space(1))) u32*)(gp_ + off_ + lane * 4),\
          (__attribute__((address_space(3))) u32*)(sb_ + off_),                 \
          16, 0, 0);                                                            \
    }                                                                           \
  } while (0)

#define LOAD_B4_INTO(R0, R1, R2, R3, PTRB)                                     \
  do {                                                                         \
    const float* Bt_ = (PTRB);                                                 \
    R0 = *reinterpret_cast<const f32x4*>(Bt_ + rowbase + 0 * 16 + q * 4);      \
    R1 = *reinterpret_cast<const f32x4*>(Bt_ + rowbase + 1 * 16 + q * 4);      \
    R2 = *reinterpret_cast<const f32x4*>(Bt_ + rowbase + 2 * 16 + q * 4);      \
    R3 = *reinterpret_cast<const f32x4*>(Bt_ + rowbase + 3 * 16 + q * 4);      \
  } while (0)

#define SB0() __builtin_amdgcn_sched_barrier(0)

#define VM_WAIT_BARRIER(NSTR)                                   \
  do {                                                          \
    SB0();                                                      \
    asm volatile("s_waitcnt vmcnt(" NSTR ")" ::: "memory");     \
    SB0();                                                      \
    __builtin_amdgcn_s_barrier();                               \
    SB0();                                                      \
  } while (0)

// ---------------- fold: (pa,pb) <- fold of nElem (A,B) elements ----------------
// Step j consumes A(j+1) [sA[cCur]] and B(j+1) [regs C*]; issues B(j+2)->I*
// and A(j+3)->sA[cTgt]. End barrier: vmcnt(8) leaves {B(j+2), A(j+3)} in
// flight, guarantees A(j+2) staged for the next step.
#define FOLD_STEP(J, C0, C1, C2, C3, I0, I1, I2, I3)                          \
  do {                                                                        \
    const int j_ = (J);                                                       \
    const bool more_ = (j_ + 1 < nS);                                         \
    if (more_) {                                                              \
      const int eB_ = (j_ + 2 <= eMax) ? j_ + 2 : eMax;                       \
      const int eA_ = (j_ + 3 <= eMax) ? j_ + 3 : eMax;                       \
      LOAD_B4_INTO(I0, I1, I2, I3,                                            \
                   srcB + (size_t)(e0 + (long)eB_ * elemStride) * kTile);     \
      SB0();                                                                  \
      ISSUE_A(srcA + (size_t)(e0 + (long)eA_ * elemStride) * kTile,           \
              &sA[cTgt][0]);                                                  \
      SB0();                                                                  \
    }                                                                         \
    f32x4 npa[4], npb[4];                                                     \
    npb[0] = C0; npb[1] = C1; npb[2] = C2; npb[3] = C3;                       \
    _Pragma("unroll") for (int cm = 0; cm < 4; ++cm)                          \
        npa[cm] = (f32x4){0.f, 0.f, 0.f, 0.f};                                \
    const float* sCur_ = &sA[cCur][0];                                        \
    _Pragma("unroll") for (int ks = 0; ks < 2; ++ks) {                        \
      u32 pa01h, pa01l, pa23h, pa23l, qa01h, qa01l, qa23h, qa23l;             \
      u32 pb01h, pb01l, pb23h, pb23l, qb01h, qb01l, qb23h, qb23l;             \
      pk_split(apa[2 * ks][0], apa[2 * ks][1], pa01h, pa01l);                 \
      pk_split(apa[2 * ks][2], apa[2 * ks][3], pa23h, pa23l);                 \
      pk_split(apa[2 * ks + 1][0], apa[2 * ks + 1][1], qa01h, qa01l);         \
      pk_split(apa[2 * ks + 1][2], apa[2 * ks + 1][3], qa23h, qa23l);         \
      pk_split(apb[2 * ks][0], apb[2 * ks][1], pb01h, pb01l);                 \
      pk_split(apb[2 * ks][2], apb[2 * ks][3], pb23h, pb23l);                 \
      pk_split(apb[2 * ks + 1][0], apb[2 * ks + 1][1], qb01h, qb01l);         \
      pk_split(apb[2 * ks + 1][2], apb[2 * ks + 1][3], qb23h, qb23l);         \
      const short8 bah = gather_frag(pa01h, pa23h, qa01h, qa23h, ad0, ad1, lowh); \
      const short8 bal = gather_frag(pa01l, pa23l, qa01l, qa23l, ad0, ad1, lowh); \
      const short8 bbh = gather_frag(pb01h, pb23h, qb01h, qb23h, ad0, ad1, lowh); \
      const short8 bbl = gather_frag(pb01l, pb23l, qb01l, qb23l, ad0, ad1, lowh); \
      _Pragma("unroll") for (int cm = 0; cm < 4; ++cm) {                      \
        short8 ah, al;                                                        \
        read_afragT(sCur_, cm * 16 + l15, ks * 32 + q * 8, ah, al);           \
        npa[cm] = mfma16(ah, bah, npa[cm]);                                   \
        npa[cm] = mfma16(ah, bal, npa[cm]);                                   \
        npa[cm] = mfma16(al, bah, npa[cm]);                                   \
        npb[cm] = mfma16(ah, bbh, npb[cm]);                                   \
        npb[cm] = mfma16(ah, bbl, npb[cm]);                                   \
        npb[cm] = mfma16(al, bbh, npb[cm]);                                   \
      }                                                                       \
    }                                                                         \
    _Pragma("unroll") for (int cm = 0; cm < 4; ++cm) {                        \
      apa[cm] = npa[cm];                                                      \
      apb[cm] = npb[cm];                                                      \
    }                                                                         \
    if (more_) VM_WAIT_BARRIER("8");                                          \
    cCur = (cCur == 2) ? 0 : cCur + 1;                                        \
    cTgt = (cTgt == 2) ? 0 : cTgt + 1;                                        \
  } while (0)

__global__ __attribute__((amdgpu_flat_work_group_size(256, 256),
                          amdgpu_waves_per_eu(3, 4)))
void gdr_fold(const float* __restrict__ srcA, const float* __restrict__ srcB,
              float* __restrict__ dstA, float* __restrict__ dstB,
              int perChain, long chainBase, long idxBase, long elemStride,
              int nElem) {
  __shared__ float sA[3][4096];

  const int tid = threadIdx.x;
  const int lane = tid & 63, w = tid >> 6;
  const int q = lane >> 4, l15 = lane & 15;
  const int bh = blockIdx.x / perChain, id = blockIdx.x % perChain;
  const long e0 = (long)bh * chainBase + (long)id * idxBase;
  const int rowbase = (w * 16 + l15) * 64;
  const int ad0 = (l15 + ((lane >> 4) & 1) * 32) * 4;
  const int ad1 = ad0 + 64;
  const bool lowh = lane < 32;
  const int nS = nElem - 1;
  const int eMax = nElem - 1;

  f32x4 apa[4], apb[4];
  {
    const float* At = srcA + (size_t)e0 * kTile;
    const float* Bt = srcB + (size_t)e0 * kTile;
#pragma unroll
    for (int cm = 0; cm < 4; ++cm) {
      apa[cm] = *reinterpret_cast<const f32x4*>(At + rowbase + cm * 16 + q * 4);
      apb[cm] = *reinterpret_cast<const f32x4*>(Bt + rowbase + cm * 16 + q * 4);
    }
  }

  f32x4 r0a, r0b, r0c, r0d;  // B register set 0
  f32x4 r1a, r1b, r1c, r1d;  // B register set 1

  // prologue: B(1)->set1, A(1)->sA[1], A(2)->sA[2]; vmcnt(4) leaves A(2) in
  // flight, guarantees A(1) staged.
  {
    const int e2 = (2 <= eMax) ? 2 : eMax;
    LOAD_B4_INTO(r1a, r1b, r1c, r1d, srcB + (size_t)(e0 + elemStride) * kTile);
    SB0();
    ISSUE_A(srcA + (size_t)(e0 + elemStride) * kTile, &sA[1][0]);
    ISSUE_A(srcA + (size_t)(e0 + (long)e2 * elemStride) * kTile, &sA[2][0]);
    SB0();
    asm volatile("s_waitcnt vmcnt(4)" ::: "memory");
    SB0();
    __builtin_amdgcn_s_barrier();
    SB0();
  }

  int cCur = 1, cTgt = 0;
  int j = 0;
  while (true) {
    FOLD_STEP(j, r1a, r1b, r1c, r1d, r0a, r0b, r0c, r0d);  // consume set1, issue set0
    if (++j >= nS) break;
    FOLD_STEP(j, r0a, r0b, r0c, r0d, r1a, r1b, r1c, r1d);  // consume set0, issue set1
    if (++j >= nS) break;
  }

  float* pao = dstA + (size_t)blockIdx.x * kTile;
  float* pbo = dstB + (size_t)blockIdx.x * kTile;
#pragma unroll
  for (int cm = 0; cm < 4; ++cm) {
    *reinterpret_cast<f32x4*>(pao + rowbase + cm * 16 + q * 4) = apa[cm];
    *reinterpret_cast<f32x4*>(pbo + rowbase + cm * 16 + q * 4) = apb[cm];
  }
}

// ---------------- scan: apply nSteps elements, write states into out ----------------
// Step i consumes A(i) [sA[cCur]] and B(i) [regs C*]; issues B(i+1)->I* and
// A(i+2)->sA[cTgt]; stores state. End barrier vmcnt(12) (4 stores + 8 loads
// stay in flight), guarantees A(i+1) staged.
#define SCAN_STEP(I, C0, C1, C2, C3, I0, I1, I2, I3)                          \
  do {                                                                        \
    const int i_ = (I);                                                       \
    const bool more_ = (i_ + 1 < nSteps);                                     \
    if (more_) {                                                              \
      const int eB_ = (i_ + 1 <= eMax) ? i_ + 1 : eMax;                       \
      const int eA_ = (i_ + 2 <= eMax) ? i_ + 2 : eMax;                       \
      LOAD_B4_INTO(I0, I1, I2, I3,                                            \
                   srcB + (size_t)(e0 + (long)eB_ * elemStride) * kTile);     \
      SB0();                                                                  \
      ISSUE_A(srcA + (size_t)(e0 + (long)eA_ * elemStride) * kTile,           \
              &sA[cTgt][0]);                                                  \
      SB0();                                                                  \
    }                                                                         \
    f32x4 nacc[4];                                                            \
    nacc[0] = C0; nacc[1] = C1; nacc[2] = C2; nacc[3] = C3;                   \
    const float* sCur_ = &sA[cCur][0];                                        \
    _Pragma("unroll") for (int ks = 0; ks < 2; ++ks) {                        \
      u32 p01h, p01l, p23h, p23l, q01h, q01l, q23h, q23l;                     \
      pk_split(acc[2 * ks][0], acc[2 * ks][1], p01h, p01l);                   \
      pk_split(acc[2 * ks][2], acc[2 * ks][3], p23h, p23l);                   \
      pk_split(acc[2 * ks + 1][0], acc[2 * ks + 1][1], q01h, q01l);           \
      pk_split(acc[2 * ks + 1][2], acc[2 * ks + 1][3], q23h, q23l);           \
      const short8 bfh = gather_frag(p01h, p23h, q01h, q23h, ad0, ad1, lowh); \
      const short8 bfl = gather_frag(p01l, p23l, q01l, q23l, ad0, ad1, lowh); \
      _Pragma("unroll") for (int cm = 0; cm < 4; ++cm) {                      \
        short8 ah, al;                                                        \
        read_afragT(sCur_, cm * 16 + l15, ks * 32 + q * 8, ah, al);           \
        nacc[cm] = mfma16(ah, bfh, nacc[cm]);                                 \
        nacc[cm] = mfma16(ah, bfl, nacc[cm]);                                 \
        nacc[cm] = mfma16(al, bfh, nacc[cm]);                                 \
      }                                                                       \
    }                                                                         \
    const int t_ = tBase + (i_ + 1) * tStep - 1;                              \
    float* o_ = out + ((size_t)t_ * kBH + bh) * kTile;                        \
    _Pragma("unroll") for (int cm = 0; cm < 4; ++cm) {                        \
      *reinterpret_cast<f32x4*>(o_ + rowbase + cm * 16 + q * 4) = nacc[cm];   \
      acc[cm] = nacc[cm];                                                     \
    }                                                                         \
    if (more_) VM_WAIT_BARRIER("12");                                         \
    cCur = (cCur == 2) ? 0 : cCur + 1;                                        \
    cTgt = (cTgt == 2) ? 0 : cTgt + 1;                                        \
  } while (0)

__global__ __attribute__((amdgpu_flat_work_group_size(256, 256),
                          amdgpu_waves_per_eu(3, 4)))
void gdr_scan(const float* __restrict__ srcA, const float* __restrict__ srcB,
              const float* __restrict__ S0, float* __restrict__ out,
              int perChain, long chainBase, long idxBase, long elemStride,
              int nSteps, int tbMul, int tStep) {
  __shared__ float sA[3][4096];

  const int tid = threadIdx.x;
  const int lane = tid & 63, w = tid >> 6;
  const int q = lane >> 4, l15 = lane & 15;
  const int bh = blockIdx.x / perChain, id = blockIdx.x % perChain;
  const long e0 = (long)bh * chainBase + (long)id * idxBase;
  const int tBase = id * tbMul;
  const int rowbase = (w * 16 + l15) * 64;
  const int ad0 = (l15 + ((lane >> 4) & 1) * 32) * 4;
  const int ad1 = ad0 + 64;
  const bool lowh = lane < 32;
  const int eMax = nSteps - 1;

  f32x4 acc[4];
  {
    const float* Sb = (tBase == 0) ? (S0 + (size_t)bh * kTile)
                                   : (out + ((size_t)(tBase - 1) * kBH + bh) * kTile);
#pragma unroll
    for (int cm = 0; cm < 4; ++cm)
      acc[cm] = *reinterpret_cast<const f32x4*>(Sb + rowbase + cm * 16 + q * 4);
  }

  f32x4 r0a, r0b, r0c, r0d;
  f32x4 r1a, r1b, r1c, r1d;

  // prologue: B(0)->set0, A(0)->sA[0], A(1)->sA[1]; vmcnt(4) leaves A(1).
  {
    const int e1 = (1 <= eMax) ? 1 : eMax;
    LOAD_B4_INTO(r0a, r0b, r0c, r0d, srcB + (size_t)e0 * kTile);
    SB0();
    ISSUE_A(srcA + (size_t)e0 * kTile, &sA[0][0]);
    ISSUE_A(srcA + (size_t)(e0 + (long)e1 * elemStride) * kTile, &sA[1][0]);
    SB0();
    asm volatile("s_waitcnt vmcnt(4)" ::: "memory");
    SB0();
    __builtin_amdgcn_s_barrier();
    SB0();
  }

  int cCur = 0, cTgt = 2;
  int i = 0;
  while (true) {
    SCAN_STEP(i, r0a, r0b, r0c, r0d, r1a, r1b, r1c, r1d);  // consume set0, issue set1
    if (++i >= nSteps) break;
    SCAN_STEP(i, r1a, r1b, r1c, r1d, r0a, r0b, r0c, r0d);  // consume set1, issue set0
    if (++i >= nSteps) break;
  }
}

extern "C" void kernel_launch(void* const* d_in, const int* in_sizes, int n_in,
                              void* d_out, int out_size, void* d_ws, size_t ws_size,
                              hipStream_t stream) {
  const float* A  = (const float*)d_in[0];
  const float* Bm = (const float*)d_in[1];
  const float* S0 = (const float*)d_in[2];
  float* out = (float*)d_out;

  // workspace: PA[64*16], PB[64*16] tiles of 16 KB = 32 MB
  float* PA = (float*)d_ws;
  float* PB = PA + (size_t)kBH * kNC * kTile;

  // K1: chunk summaries. elements (ck*8+i)*64+bh, i=0..7
  gdr_fold<<<dim3(kBH * kNC), dim3(256), 0, stream>>>(
      A, Bm, PA, PB, kNC, 1L, (long)kCH * kBH, (long)kBH, kCH);
  // K2: scan 16 summaries (tiles bh*16+i); writes t = (i+1)*8-1 (7,15,...,127)
  gdr_scan<<<dim3(kBH), dim3(256), 0, stream>>>(
      PA, PB, S0, out, 1, (long)kNC, 0L, 1L, kNC, 0, kCH);
  // K3: in-chunk recurrence; elements (ck*8+i)*64+bh, start out[ck*8-1]/S0,
  //     writes t = ck*8+i for i=0..6
  gdr_scan<<<dim3(kBH * kNC), dim3(256), 0, stream>>>(
      A, Bm, S0, out, kNC, 1L, (long)kCH * kBH, (long)kBH, kCH - 1, kCH, 1);
}